// Round 6
// baseline (194.391 us; speedup 1.0000x reference)
//
#include <hip/hip_runtime.h>
#include <math.h>

#define NB 2048
#define DEPTH 8

// ws layout (float offsets)
#define FTABW   0        // [d][g][l][q][8]  8*5*64*4*8 = 81920
#define BF01W   81920    // [l][n][8]        64*12*8    = 6144
#define BFFW    88064    // [f][l][n][8]     5*64*4*8   = 10240
#define ACT4    98304    // [d][k] float4    2048*4     = 8192
#define PHYSWV  106496   // [d][l][k] int    8*64*8     = 4096
#define PHYSRV  110592   // [d][l][m] int    8*64*4     = 2048
#define PHYSO3  112640   // [l][n][m] int    64*12*4    = 3072
// total 115712 floats = 462848 bytes

__device__ __forceinline__ void write_rec(float* o,
                                          const float* angA, int pA0, int pA1,
                                          const float* angB, int pB0, int pB1) {
    float s, c;
    sincosf(angA[pA0], &s, &c); o[0] = c; o[1] = s;
    sincosf(angA[pA1], &s, &c); o[2] = c; o[3] = s;
    sincosf(angB[pB0], &s, &c); o[4] = c; o[5] = s;
    sincosf(angB[pB1], &s, &c); o[6] = c; o[7] = s;
}

// ---------------- precompute: all rotation tables + act constants ----------------
__global__ void tab_precompute(const float* __restrict__ angles,
                               const float* __restrict__ bf_angles,
                               const float* __restrict__ act_bias,
                               const float* __restrict__ act_curv,
                               float* __restrict__ ws) {
    int r = blockIdx.x * 256 + threadIdx.x;
    if (r < 10240) {
        // sponge fused: record = ((d*5+g)*64 + l)*4 + q
        int q = r & 3, l = (r >> 2) & 63, gg = r >> 8;
        int d = gg / 5, g = gg - 5 * d;
        int v = l + 64 * q, tl = v & 127, th = v >> 7, a = 2 * tl + th;
        const float* A = angles + (d * 10 + 2 * g) * 512;
        const float* B = angles + (d * 10 + 2 * g + 1) * 512;
        write_rec(ws + FTABW + r * 8, A, a, a + 256, B, 2 * a, 2 * a + 1);
    } else if (r < 11008) {
        int r2 = r - 10240;                 // [l][n]
        int l = r2 / 12, n = r2 - 12 * l;
        int a = l + 64 * n;
        write_rec(ws + BF01W + r2 * 8, bf_angles, a, a + 768,
                  bf_angles + 1536, 2 * a, 2 * a + 1);
    } else if (r < 12288) {
        int r3 = r - 11008;                 // [f][l][n]
        int f = r3 >> 8, l = (r3 >> 2) & 63, n = r3 & 3;
        int vt = l + 64 * n;
        int P;
        if (f == 0) P = 3 * vt;
        else if (f < 4) { int k = 8 - 2 * f;
                          P = ((vt >> (2 * f)) * (768 >> k)) + (vt & ((256 >> k) - 1)); }
        else P = vt;
        write_rec(ws + BFFW + r3 * 8, bf_angles + (2 + 2 * f) * 1536, P, P + 768,
                  bf_angles + (3 + 2 * f) * 1536, 2 * P, 2 * P + 1);
    } else if (r < 14336) {
        int ida = r - 12288;                // d*256 + k
        float cu = act_curv[ida];
        float c  = 0.5f * (cu + sqrtf(cu * cu + 1.0f));
        ((float4*)(ws + ACT4))[ida] = make_float4(act_bias[ida], c, 1.0f / c, 0.0f);
    }
}

// ---------------- precompute: compacted mem slots + per-lane index tables ---------
__global__ void phys_precompute(const int* __restrict__ recall_idx,
                                const int* __restrict__ out_mem_idx,
                                float* __restrict__ ws) {
    __shared__ int physL[4096];
    int t = threadIdx.x;   // 1024 threads, 1 block
    for (int q = 0; q < 4; ++q) {
        int v = t + q * 1024;
        int p;
        for (;;) {
            int d = v >> 9, j = v & 511;
            if (d == 0)  { p = j; break; }
            if (j < 256) { p = 256 + d * 256 + j; break; }
            v = recall_idx[(d - 1) * 256 + (j - 256)];
        }
        physL[t + q * 1024] = p;
    }
    __syncthreads();
    int* pwv = (int*)(ws + PHYSWV);
    for (int e = t; e < 4096; e += 1024) {
        int d = e >> 9, rem = e & 511, l = rem >> 3, k = rem & 7;
        pwv[e] = physL[d * 512 + l + 64 * k];
    }
    int* prv = (int*)(ws + PHYSRV);
    for (int e = t; e < 2048; e += 1024) {
        int d = e >> 8, rem = e & 255, l = rem >> 2, m = rem & 3;
        prv[e] = physL[recall_idx[d * 256 + l + 64 * m]];
    }
    int* po3 = (int*)(ws + PHYSO3);
    for (int e = t; e < 3072; e += 1024) {
        int l = e / 48, rem = e - 48 * l, n = rem >> 2, m = rem & 3;
        int a = l + 64 * n;
        int pos = (a >> 1) + (a & 1) * 1536 + 384 * m;
        po3[e] = (pos < 2048) ? physL[out_mem_idx[pos]] : 2304 + (pos - 2048);
    }
}

__device__ __forceinline__ float actf(float x, float c, float ic) {
    const float is2 = 0.70710678118654752f;
    float tt = 0.78539816339744831f * ic;
    float y0 = is2 * ic;
    float y1 = (is2 - 1.0f) * ic;
    float mid = ic * (is2 - __cosf(0.78539816339744831f + c * x));
    return x > tt ? (y0 + (x - tt)) : (x < -tt ? y1 : mid);
}

// one radix-4 quad: 2 fused stages, table record = [csA|csB]
#define QUAD(cA, cB, i0, i1, i2, i3, F0, F1, F2, F3)                     \
    { float g0 =  (cA).x * (i0) + (cA).y * (i2);                         \
      float g2 = -(cA).y * (i0) + (cA).x * (i2);                         \
      float g1 =  (cA).z * (i1) + (cA).w * (i3);                         \
      float g3 = -(cA).w * (i1) + (cA).z * (i3);                         \
      F0 =  (cB).x * g0 + (cB).y * g1;                                   \
      F2 = -(cB).y * g0 + (cB).x * g1;                                   \
      F1 =  (cB).z * g2 + (cB).w * g3;                                   \
      F3 = -(cB).w * g2 + (cB).z * g3; }

// ---------------- main kernel: one row per wave, barrier-free core ---------------
__launch_bounds__(256, 2)
__global__ void sponge_kernel(const float* __restrict__ X,
                              const float* __restrict__ scales,
                              const float* __restrict__ ws,
                              float* __restrict__ out) {
    __shared__ float lds[13312];         // 4 wave-private regions of 3328 floats
    const int t = threadIdx.x;
    const int l = t & 63;
    const int w = t >> 6;
    const int row = blockIdx.x * 4 + w;
    float* R = lds + w * 3328;           // memb [0,2304)
    float* E = R + 2304;                 // exch [0,1024)

    // initial holdings: h[j] = s[l + 64j]
    float h[16];
#pragma unroll
    for (int j = 0; j < 16; ++j) {
        int idx = l + 64 * j;
        h[j] = X[(size_t)row * 1024 + idx] * scales[idx];
    }

    for (int d = 0; d < DEPTH; ++d) {
        // ---- group 1: inputs from registers (repack/init layout) ----
        {
            const float4* fp = (const float4*)(ws + FTABW + (size_t)((d * 5) * 64 + l) * 32);
            float f00,f01,f02,f03, f10,f11,f12,f13, f20,f21,f22,f23, f30,f31,f32,f33;
            QUAD(fp[0], fp[1], h[0], h[2],  h[4],  h[6],  f00, f01, f02, f03);
            QUAD(fp[2], fp[3], h[1], h[3],  h[5],  h[7],  f10, f11, f12, f13);
            QUAD(fp[4], fp[5], h[8], h[10], h[12], h[14], f20, f21, f22, f23);
            QUAD(fp[6], fp[7], h[9], h[11], h[13], h[15], f30, f31, f32, f33);
            *(float4*)(E + 4 * l)       = make_float4(f00, f01, f20, f21);
            *(float4*)(E + 4 * l + 256) = make_float4(f10, f11, f30, f31);
            *(float4*)(E + 4 * l + 512) = make_float4(f02, f03, f22, f23);
            *(float4*)(E + 4 * l + 768) = make_float4(f12, f13, f32, f33);
        }
        // ---- groups 2..5: read holdings from exch (in-place, wave-ordered) ----
#pragma unroll
        for (int g = 1; g < 5; ++g) {
            const float4* fp = (const float4*)(ws + FTABW + (size_t)((d * 5 + g) * 64 + l) * 32);
            float a0 = E[l],       a1 = E[l + 128], a2 = E[l + 256], a3 = E[l + 384];
            float b0 = E[l + 64],  b1 = E[l + 192], b2 = E[l + 320], b3 = E[l + 448];
            float c0 = E[l + 512], c1 = E[l + 640], c2 = E[l + 768], c3 = E[l + 896];
            float e0 = E[l + 576], e1 = E[l + 704], e2 = E[l + 832], e3 = E[l + 960];
            float f00,f01,f02,f03, f10,f11,f12,f13, f20,f21,f22,f23, f30,f31,f32,f33;
            QUAD(fp[0], fp[1], a0, a1, a2, a3, f00, f01, f02, f03);
            QUAD(fp[2], fp[3], b0, b1, b2, b3, f10, f11, f12, f13);
            QUAD(fp[4], fp[5], c0, c1, c2, c3, f20, f21, f22, f23);
            QUAD(fp[6], fp[7], e0, e1, e2, e3, f30, f31, f32, f33);
            *(float4*)(E + 4 * l)       = make_float4(f00, f01, f20, f21);
            *(float4*)(E + 4 * l + 256) = make_float4(f10, f11, f30, f31);
            *(float4*)(E + 4 * l + 512) = make_float4(f02, f03, f22, f23);
            *(float4*)(E + 4 * l + 768) = make_float4(f12, f13, f32, f33);
        }
        // ---- repack (wave-private; scatter before recall in program order) ----
        {
            const int4* pw = (const int4*)((const int*)(ws + PHYSWV) + (d * 64 + l) * 8);
            int4 pw0 = pw[0], pw1 = pw[1];
            float z0 = E[l],       z1 = E[l + 64],  z2 = E[l + 128], z3 = E[l + 192];
            float z4 = E[l + 256], z5 = E[l + 320], z6 = E[l + 384], z7 = E[l + 448];
            R[pw0.x] = z0; R[pw0.y] = z1; R[pw0.z] = z2; R[pw0.w] = z3;
            R[pw1.x] = z4; R[pw1.y] = z5; R[pw1.z] = z6; R[pw1.w] = z7;
            // activation -> h[0..7]
            int k0 = l >> 1;
            float sgn = (l & 1) ? -1.0f : 1.0f;
            const float4* ac = (const float4*)(ws + ACT4) + d * 256 + k0;
#pragma unroll
            for (int j = 0; j < 8; ++j) {
                float  xz = E[512 + k0 + 32 * j];
                float4 aa = ac[32 * j];
                h[j] = actf(sgn * (xz + aa.x), aa.y, aa.z);
            }
            // keep -> h[8..11]
            h[8]  = E[l + 768]; h[9]  = E[l + 832];
            h[10] = E[l + 896]; h[11] = E[l + 960];
            // recall -> h[12..15] (after scatter writes)
            int4 pr = *(const int4*)((const int*)(ws + PHYSRV) + (d * 64 + l) * 4);
            h[12] = R[pr.x]; h[13] = R[pr.y]; h[14] = R[pr.z]; h[15] = R[pr.w];
        }
        __syncthreads();   // convoy waves for L1 table locality (not needed for correctness)
    }

    // ---- stage sponge s' into exch (natural layout) ----
#pragma unroll
    for (int j = 0; j < 16; ++j) E[l + 64 * j] = h[j];

    // ---- gather fused-(0,1) inputs: 48 values, all reads before any write ----
    const int4* po = (const int4*)((const int*)(ws + PHYSO3) + l * 48);
    float pv[48];
#pragma unroll
    for (int n = 0; n < 12; ++n) {
        int4 gi = po[n];
        pv[4 * n + 0] = R[gi.x]; pv[4 * n + 1] = R[gi.y];
        pv[4 * n + 2] = R[gi.z]; pv[4 * n + 3] = R[gi.w];
    }
    // ---- fused stages (0,1): 12 quads per lane, dense writes ----
    const float4* b01 = (const float4*)(ws + BF01W) + l * 24;
#pragma unroll
    for (int n = 0; n < 12; ++n) {
        float4 cA = b01[2 * n], cB = b01[2 * n + 1];
        float y0, y1, y2, y3;
        QUAD(cA, cB, pv[4 * n], pv[4 * n + 1], pv[4 * n + 2], pv[4 * n + 3],
             y0, y1, y2, y3);
        int a = l + 64 * n;
        *(float2*)(R + 2 * a)        = make_float2(y0, y1);
        *(float2*)(R + 2 * a + 1536) = make_float2(y2, y3);
    }

    // ---- fused pruned double-stages (2,3) (4,5) (6,7) (8,9) ----
#pragma unroll
    for (int f = 0; f < 4; ++f) {
        int PP[4]; float x1p[4], x1q[4], x2p[4], x2q[4];
#pragma unroll
        for (int n = 0; n < 4; ++n) {
            int vt = l + 64 * n;
            int P;
            if (f == 0) P = 3 * vt;
            else { const int k = 8 - 2 * f;
                   P = ((vt >> (2 * f)) * (768 >> k)) + (vt & ((256 >> k) - 1)); }
            PP[n] = P;
            int base = (P >> 1) + (P & 1) * 1536;
            x1p[n] = R[base];        x1q[n] = R[base + 384];
            x2p[n] = R[base + 768];  x2q[n] = R[base + 1152];
        }
        const float4* bf = (const float4*)(ws + BFFW) + (f * 256 + l * 4) * 2;
#pragma unroll
        for (int n = 0; n < 4; ++n) {
            float4 cS = bf[2 * n], cT = bf[2 * n + 1];
            float o1P =  cS.x * x1p[n] + cS.y * x2p[n];
            float o2P = -cS.y * x1p[n] + cS.x * x2p[n];
            float o1Q =  cS.z * x1q[n] + cS.w * x2q[n];
            float o2Q = -cS.w * x1q[n] + cS.z * x2q[n];
            float y0 =  cT.x * o1P + cT.y * o1Q;
            float y2 = -cT.y * o1P + cT.x * o1Q;
            float y1 =  cT.z * o2P + cT.w * o2Q;
            float y3 = -cT.w * o2P + cT.z * o2Q;
            *(float2*)(R + 2 * PP[n])        = make_float2(y0, y1);
            *(float2*)(R + 2 * PP[n] + 1536) = make_float2(y2, y3);
        }
    }

    // ---- fused (10,11) + output store ----
    {
        const float4* bf = (const float4*)(ws + BFFW) + (4 * 256 + l * 4) * 2;
#pragma unroll
        for (int n = 0; n < 4; ++n) {
            int vt = l + 64 * n;
            int base = (vt >> 1) + (vt & 1) * 1536;
            float x1p = R[base],       x1q = R[base + 384];
            float x2p = R[base + 768], x2q = R[base + 1152];
            float4 cS = bf[2 * n], cT = bf[2 * n + 1];
            float o1P =  cS.x * x1p + cS.y * x2p;
            float o2P = -cS.y * x1p + cS.x * x2p;
            float o1Q =  cS.z * x1q + cS.w * x2q;
            float o2Q = -cS.w * x1q + cS.z * x2q;
            *(float2*)(out + (size_t)row * 512 + 2 * vt) =
                make_float2(cT.x * o1P + cT.y * o1Q, cT.z * o2P + cT.w * o2Q);
        }
    }
}

extern "C" void kernel_launch(void* const* d_in, const int* in_sizes, int n_in,
                              void* d_out, int out_size, void* d_ws, size_t ws_size,
                              hipStream_t stream) {
    const float* X          = (const float*)d_in[0];
    const float* scales     = (const float*)d_in[1];
    const float* angles     = (const float*)d_in[2];
    const float* act_bias   = (const float*)d_in[3];
    // d_in[4] act_activation — unused by the reference
    const float* act_curv   = (const float*)d_in[5];
    const float* bf_angles  = (const float*)d_in[6];
    // d_in[7] shuffle_perm — structural perfect shuffle, hardcoded
    const int*   recall_idx  = (const int*)d_in[8];
    const int*   out_mem_idx = (const int*)d_in[9];
    // d_in[10] bf_perm — structural perfect shuffle, hardcoded

    float* ws = (float*)d_ws;   // 462848 bytes used

    tab_precompute<<<56, 256, 0, stream>>>(angles, bf_angles, act_bias, act_curv, ws);
    phys_precompute<<<1, 1024, 0, stream>>>(recall_idx, out_mem_idx, ws);
    sponge_kernel<<<NB / 4, 256, 0, stream>>>(X, scales, ws, (float*)d_out);
}

// Round 7
// 122.263 us; speedup vs baseline: 1.5899x; 1.5899x over previous
//
#include <hip/hip_runtime.h>
#include <math.h>

#define NB 2048
#define DEPTH 8

// ws layout (float offsets)
#define FTAB_OFF    0        // sponge fused cs: 8*5*256*8 = 81920 floats
#define BF01_OFF    81920    // bf stages 0-1: 256*3*2 float4 = 6144 floats
#define BFF_OFF     88064    // bf fused (2,3)..(10,11): 5*256*8 = 10240 floats
#define ACT4_OFF    98304    // act table: 2048 float4 = 8192 floats
#define PHYSA_OFF   106496   // int2 per (d,t): mem scatter targets, 4096 ints
#define PHYSR_OFF   110592   // phys_recall[2048] int
#define PHYSO2_OFF  112640   // per-thread pre-gather [256*12] int
// total 115712 floats = 462848 bytes

// ---------------- single merged setup dispatch ----------------
__global__ void setup_kernel(const float* __restrict__ angles,
                             const float* __restrict__ bf_angles,
                             const float* __restrict__ act_bias,
                             const float* __restrict__ act_curv,
                             const int* __restrict__ recall_idx,
                             const int* __restrict__ out_mem_idx,
                             float* __restrict__ ws) {
    __shared__ int physL[4096];
    if (blockIdx.x < 200) {
        int id = blockIdx.x * 256 + threadIdx.x;
        if (id < 40960) {
            // sponge fused table: id = ((d*5+g)*256 + t)*4 + w
            int w = id & 3, t = (id >> 2) & 255, dg = id >> 10;
            int d = dg / 5, g = dg - 5 * d;
            int a = 2 * (t & 127) + (t >> 7);
            int pair = (w == 0) ? a : (w == 1) ? (a + 256)
                     : (w == 2) ? (2 * a) : (2 * a + 1);
            int st = 2 * g + (w >> 1);
            float ang = angles[(d * 10 + st) * 512 + pair];
            float s, c; sincosf(ang, &s, &c);
            ws[FTAB_OFF + 2 * id]     = c;
            ws[FTAB_OFF + 2 * id + 1] = s;
        } else if (id < 44032) {
            // BF01: e = (t*3+i)*4 + w ; a = t+256i
            int e = id - 40960;
            int w = e & 3; int ti = e >> 2;
            int t = ti / 3; int i = ti - 3 * t;
            int a = t + 256 * i;
            int pair = (w == 0) ? a : (w == 1) ? (a + 768)
                     : (w == 2) ? (2 * a) : (2 * a + 1);
            int stage = (w < 2) ? 0 : 1;
            float ang = bf_angles[stage * 1536 + pair];
            float s, c; sincosf(ang, &s, &c);
            ws[BF01_OFF + 2 * e]     = c;
            ws[BF01_OFF + 2 * e + 1] = s;
        } else if (id < 49152) {
            // BFF: e = (f*256+t)*4 + w ; fused stages (2+2f, 3+2f)
            int e = id - 44032;
            int f = e >> 10; int rem = e & 1023; int t = rem >> 2; int w = rem & 3;
            int P;
            if (f == 0) P = 3 * t;
            else if (f < 4) { int k = 8 - 2 * f;
                              P = ((t >> (2 * f)) * (768 >> k)) + (t & ((256 >> k) - 1)); }
            else P = t;
            int pair = (w == 0) ? P : (w == 1) ? (P + 768)
                     : (w == 2) ? (2 * P) : (2 * P + 1);
            int stage = (w < 2) ? (2 + 2 * f) : (3 + 2 * f);
            float ang = bf_angles[stage * 1536 + pair];
            float s, c; sincosf(ang, &s, &c);
            ws[BFF_OFF + 2 * e]     = c;
            ws[BFF_OFF + 2 * e + 1] = s;
        } else if (id < 51200) {
            int ida = id - 49152;              // d*256 + k
            float cu = act_curv[ida];
            float c  = 0.5f * (cu + sqrtf(cu * cu + 1.0f));
            ((float4*)(ws + ACT4_OFF))[ida] =
                make_float4(act_bias[ida], c, 1.0f / c, 0.0f);
        }
    } else {
        // phys block: compacted mem slot allocation (2304 phys slots)
        int tid = threadIdx.x;
        for (int e = tid; e < 4096; e += 256) {
            int v = e, p;
            for (;;) {
                int d = v >> 9, j = v & 511;
                if (d == 0)  { p = j; break; }
                if (j < 256) { p = 256 + d * 256 + j; break; }
                v = recall_idx[(d - 1) * 256 + (j - 256)];
            }
            physL[e] = p;
        }
        __syncthreads();
        int* pa = (int*)(ws + PHYSA_OFF);
        for (int e = tid; e < 2048; e += 256) {
            int d = e >> 8, t = e & 255;
            int a = 2 * (t & 127) + (t >> 7);
            pa[2 * e]     = physL[d * 512 + 2 * a];
            pa[2 * e + 1] = physL[d * 512 + 2 * a + 1];
        }
        int* pr = (int*)(ws + PHYSR_OFF);
        for (int e = tid; e < 2048; e += 256)
            pr[e] = physL[recall_idx[e]];
        int* po = (int*)(ws + PHYSO2_OFF);
        for (int e = tid; e < 3072; e += 256) {
            int tt = e / 12; int r = e - 12 * tt; int i = r >> 2; int k = r & 3;
            int a = tt + 256 * i;
            int tl2 = a >> 1, th2 = a & 1;
            int pos = tl2 + 1536 * th2 + 384 * k;
            po[e] = (pos < 2048) ? physL[out_mem_idx[pos]] : 2304 + (pos - 2048);
        }
    }
}

__device__ __forceinline__ float actf(float x, float c, float ic) {
    const float is2 = 0.70710678118654752f;
    float tt = 0.78539816339744831f * ic;
    float y0 = is2 * ic;
    float y1 = (is2 - 1.0f) * ic;
    float mid = ic * (is2 - __cosf(0.78539816339744831f + c * x));
    return x > tt ? (y0 + (x - tt)) : (x < -tt ? y1 : mid);
}

// exchange layout: tau(p) = 4*((p&511)>>1) + 2*(p>>9) + (p&1); bank XOR-fold bit7->bit2
__device__ __forceinline__ int xf(int A) { return A ^ (((A >> 7) & 1) << 2); }

// ---------------- main kernel: 2 rows per block ------------------------------------
__launch_bounds__(256, 4)
__global__ void sponge_kernel(const float* __restrict__ X,
                              const float* __restrict__ scales,
                              const float* __restrict__ ws,
                              float* __restrict__ out) {
    __shared__ float lds[8704];          // 34816 B -> 4 blocks/CU
    float* L0 = lds;                     // row A: memb [0,2304), exch [2304,4352)
    float* L1 = lds + 4352;              // row B
    const int t = threadIdx.x;
    const int rowA = blockIdx.x * 2;

    const float4* bf01  = (const float4*)(ws + BF01_OFF);
    const float4* bff   = (const float4*)(ws + BFF_OFF);
    const float4* act4  = (const float4*)(ws + ACT4_OFF);
    const int2* physA  = (const int2*)(ws + PHYSA_OFF);
    const int*  physr  = (const int*)(ws + PHYSR_OFF);
    const int*  physo2 = (const int*)(ws + PHYSO2_OFF);

    const int tl = t & 127, th = t >> 7;
    const int b  = tl + th * 512;        // holdings {b+128m}
    const int a  = 2 * tl + th;          // write base (a in [0,256))

    const int wq = xf(4 * a);                              // b128 write base
    const int rb = xf(4 * (tl >> 1) + (tl & 1) + 2 * th);  // read base, +256m
    const int u  = t - 128;
    int za0 = 0, za1 = 0, za2 = 0, za3 = 0, kb = 0;
    if (t < 128) {
        int k0 = t >> 1;
        int zb = 4 * (k0 >> 1) + (k0 & 1) + 2;
        za0 = xf(zb); za1 = xf(zb + 128); za2 = xf(zb + 256); za3 = xf(zb + 384);
    } else {
        kb = xf(512 + 4 * (u >> 1) + 2 + (u & 1));   // keep reads: kb, kb+256
    }

    float hA0, hA1, hA2, hA3, hB0, hB1, hB2, hB3;
    {
        const float* Xr0 = X + (size_t)rowA * 1024;
        const float* Xr1 = Xr0 + 1024;
        float s0 = scales[b], s1 = scales[b + 128];
        float s2 = scales[b + 256], s3 = scales[b + 384];
        hA0 = Xr0[b] * s0; hA1 = Xr0[b + 128] * s1;
        hA2 = Xr0[b + 256] * s2; hA3 = Xr0[b + 384] * s3;
        hB0 = Xr1[b] * s0; hB1 = Xr1[b + 128] * s1;
        hB2 = Xr1[b + 256] * s2; hB3 = Xr1[b + 384] * s3;
    }

    int woff = 2304, roff = 3328;
    const float4* ft = (const float4*)(ws + FTAB_OFF) + 2 * t;

#define DQUAD(cA, cB, i0, i1, i2, i3, F0, F1, F2, F3)                    \
    { float g0 =  (cA).x * (i0) + (cA).y * (i2);                         \
      float g2 = -(cA).y * (i0) + (cA).x * (i2);                         \
      float g1 =  (cA).z * (i1) + (cA).w * (i3);                         \
      float g3 = -(cA).w * (i1) + (cA).z * (i3);                         \
      F0 =  (cB).x * g0 + (cB).y * g1;                                   \
      F2 = -(cB).y * g0 + (cB).x * g1;                                   \
      F1 =  (cB).z * g2 + (cB).w * g3;                                   \
      F3 = -(cB).w * g2 + (cB).z * g3; }

    for (int d = 0; d < DEPTH; ++d) {
        for (int g = 0; g < 5; ++g) {
            float4 csA = ft[0], csB = ft[1]; ft += 512;
            float fA0, fA1, fA2, fA3, fB0, fB1, fB2, fB3;
            DQUAD(csA, csB, hA0, hA1, hA2, hA3, fA0, fA1, fA2, fA3);
            DQUAD(csA, csB, hB0, hB1, hB2, hB3, fB0, fB1, fB2, fB3);
            if (g < 4) {
                // quad {2a,2a+1,2a+512,2a+513} -> tau-contiguous {4a..4a+3}
                *(float4*)(L0 + woff + wq) = make_float4(fA0, fA1, fA2, fA3);
                *(float4*)(L1 + woff + wq) = make_float4(fB0, fB1, fB2, fB3);
                { int tmp = woff; woff = roff; roff = tmp; }
                __syncthreads();
                const float* e0 = L0 + roff + rb;
                const float* e1 = L1 + roff + rb;
                hA0 = e0[0]; hA1 = e0[256]; hA2 = e0[512]; hA3 = e0[768];
                hB0 = e1[0]; hB1 = e1[256]; hB2 = e1[512]; hB3 = e1[768];
            } else {
                // f0,f1 are the mem half (2a,2a+1 < 512): scatter direct to memb
                int2 pm = physA[d * 256 + t];
                L0[pm.x] = fA0; L0[pm.y] = fA1;
                L1[pm.x] = fB0; L1[pm.y] = fB1;
                *(float2*)(L0 + woff + wq + 2) = make_float2(fA2, fA3);
                *(float2*)(L1 + woff + wq + 2) = make_float2(fB2, fB3);
                { int tmp = woff; woff = roff; roff = tmp; }
                int r0 = 0, r1 = 0;
                float4 a0, a1, a2, a3;
                if (t < 128) {
                    int k0 = t >> 1;
                    a0 = act4[d * 256 + k0];
                    a1 = act4[d * 256 + k0 + 64];
                    a2 = act4[d * 256 + k0 + 128];
                    a3 = act4[d * 256 + k0 + 192];
                } else {
                    r0 = physr[d * 256 + u];
                    r1 = physr[d * 256 + u + 128];
                }
                __syncthreads();         // exchange + mem scatter visible
                const float* z0 = L0 + roff;
                const float* z1 = L1 + roff;
                if (t < 128) {
                    float sgn = (t & 1) ? -1.0f : 1.0f;
                    hA0 = actf(sgn * (z0[za0] + a0.x), a0.y, a0.z);
                    hA1 = actf(sgn * (z0[za1] + a1.x), a1.y, a1.z);
                    hA2 = actf(sgn * (z0[za2] + a2.x), a2.y, a2.z);
                    hA3 = actf(sgn * (z0[za3] + a3.x), a3.y, a3.z);
                    hB0 = actf(sgn * (z1[za0] + a0.x), a0.y, a0.z);
                    hB1 = actf(sgn * (z1[za1] + a1.x), a1.y, a1.z);
                    hB2 = actf(sgn * (z1[za2] + a2.x), a2.y, a2.z);
                    hB3 = actf(sgn * (z1[za3] + a3.x), a3.y, a3.z);
                } else {
                    hA0 = z0[kb]; hA1 = z0[kb + 256];
                    hB0 = z1[kb]; hB1 = z1[kb + 256];
                    hA2 = L0[r0]; hA3 = L0[r1];
                    hB2 = L1[r0]; hB3 = L1[r1];
                }
            }
        }
    }

    // ---- stage sponge into natural layout at [2304, 3328) ----
    L0[2304 + b] = hA0; L0[2304 + b + 128] = hA1;
    L0[2304 + b + 256] = hA2; L0[2304 + b + 384] = hA3;
    L1[2304 + b] = hB0; L1[2304 + b + 128] = hB1;
    L1[2304 + b + 256] = hB2; L1[2304 + b + 384] = hB3;
    __syncthreads();

    // ---- gather pre into 24 named scalars ----
    float vA0, vA1, vA2, vA3, vA4, vA5, vA6, vA7, vA8, vA9, vA10, vA11;
    float vB0, vB1, vB2, vB3, vB4, vB5, vB6, vB7, vB8, vB9, vB10, vB11;
    {
        int4 pg = ((const int4*)(physo2 + t * 12))[0];
        vA0 = L0[pg.x]; vA1 = L0[pg.y]; vA2 = L0[pg.z]; vA3 = L0[pg.w];
        vB0 = L1[pg.x]; vB1 = L1[pg.y]; vB2 = L1[pg.z]; vB3 = L1[pg.w];
        pg = ((const int4*)(physo2 + t * 12))[1];
        vA4 = L0[pg.x]; vA5 = L0[pg.y]; vA6 = L0[pg.z]; vA7 = L0[pg.w];
        vB4 = L1[pg.x]; vB5 = L1[pg.y]; vB6 = L1[pg.z]; vB7 = L1[pg.w];
        pg = ((const int4*)(physo2 + t * 12))[2];
        vA8 = L0[pg.x]; vA9 = L0[pg.y]; vA10 = L0[pg.z]; vA11 = L0[pg.w];
        vB8 = L1[pg.x]; vB9 = L1[pg.y]; vB10 = L1[pg.z]; vB11 = L1[pg.w];
    }
    __syncthreads();                     // all reads done before overwrite

    // ---- fused stages (0,1) in registers ----
#define BF01_STEP(i, qA0, qA1, qA2, qA3, qB0, qB1, qB2, qB3)                        \
    {                                                                               \
        float4 c01 = bf01[(t * 3 + (i)) * 2];                                       \
        float4 c23 = bf01[(t * 3 + (i)) * 2 + 1];                                   \
        float y0, y1, y2, y3;                                                       \
        DQUAD(c01, c23, qA0, qA1, qA2, qA3, y0, y1, y2, y3);                        \
        *(float2*)(L0 + 2 * t + 512 * (i))        = make_float2(y0, y1);            \
        *(float2*)(L0 + 2 * t + 512 * (i) + 1536) = make_float2(y2, y3);            \
        DQUAD(c01, c23, qB0, qB1, qB2, qB3, y0, y1, y2, y3);                        \
        *(float2*)(L1 + 2 * t + 512 * (i))        = make_float2(y0, y1);            \
        *(float2*)(L1 + 2 * t + 512 * (i) + 1536) = make_float2(y2, y3);            \
    }
    BF01_STEP(0, vA0, vA1, vA2, vA3, vB0, vB1, vB2, vB3)
    BF01_STEP(1, vA4, vA5, vA6, vA7, vB4, vB5, vB6, vB7)
    BF01_STEP(2, vA8, vA9, vA10, vA11, vB8, vB9, vB10, vB11)
#undef BF01_STEP
    __syncthreads();

    // ---- fused pruned double-stages (2,3) (4,5) (6,7) (8,9) ----
#pragma unroll
    for (int f = 0; f < 4; ++f) {
        int P;
        if (f == 0) P = 3 * t;
        else { const int k = 8 - 2 * f;
               P = ((t >> (2 * f)) * (768 >> k)) + (t & ((256 >> k) - 1)); }
        int base = (P >> 1) + (P & 1) * 1536;
        float4 csS = bff[(f * 256 + t) * 2];
        float4 csT = bff[(f * 256 + t) * 2 + 1];
        float xA1p = L0[base], xA1q = L0[base + 384];
        float xA2p = L0[base + 768], xA2q = L0[base + 1152];
        float xB1p = L1[base], xB1q = L1[base + 384];
        float xB2p = L1[base + 768], xB2q = L1[base + 1152];
        float o1P =  csS.x * xA1p + csS.y * xA2p;
        float o2P = -csS.y * xA1p + csS.x * xA2p;
        float o1Q =  csS.z * xA1q + csS.w * xA2q;
        float o2Q = -csS.w * xA1q + csS.z * xA2q;
        float yA0 =  csT.x * o1P + csT.y * o1Q;
        float yA2 = -csT.y * o1P + csT.x * o1Q;
        float yA1 =  csT.z * o2P + csT.w * o2Q;
        float yA3 = -csT.w * o2P + csT.z * o2Q;
        o1P =  csS.x * xB1p + csS.y * xB2p;
        o2P = -csS.y * xB1p + csS.x * xB2p;
        o1Q =  csS.z * xB1q + csS.w * xB2q;
        o2Q = -csS.w * xB1q + csS.z * xB2q;
        float yB0 =  csT.x * o1P + csT.y * o1Q;
        float yB2 = -csT.y * o1P + csT.x * o1Q;
        float yB1 =  csT.z * o2P + csT.w * o2Q;
        float yB3 = -csT.w * o2P + csT.z * o2Q;
        __syncthreads();
        *(float2*)(L0 + 2 * P)        = make_float2(yA0, yA1);
        *(float2*)(L0 + 2 * P + 1536) = make_float2(yA2, yA3);
        *(float2*)(L1 + 2 * P)        = make_float2(yB0, yB1);
        *(float2*)(L1 + 2 * P + 1536) = make_float2(yB2, yB3);
        __syncthreads();
    }

    // ---- fused (10,11) + output store ----
    {
        int base = (t >> 1) + (t & 1) * 1536;
        float4 csS = bff[(4 * 256 + t) * 2];
        float4 csT = bff[(4 * 256 + t) * 2 + 1];
        float x1p = L0[base], x1q = L0[base + 384];
        float x2p = L0[base + 768], x2q = L0[base + 1152];
        float o1P =  csS.x * x1p + csS.y * x2p;
        float o2P = -csS.y * x1p + csS.x * x2p;
        float o1Q =  csS.z * x1q + csS.w * x2q;
        float o2Q = -csS.w * x1q + csS.z * x2q;
        *(float2*)(out + (size_t)rowA * 512 + 2 * t) =
            make_float2(csT.x * o1P + csT.y * o1Q, csT.z * o2P + csT.w * o2Q);
        x1p = L1[base]; x1q = L1[base + 384];
        x2p = L1[base + 768]; x2q = L1[base + 1152];
        o1P =  csS.x * x1p + csS.y * x2p;
        o2P = -csS.y * x1p + csS.x * x2p;
        o1Q =  csS.z * x1q + csS.w * x2q;
        o2Q = -csS.w * x1q + csS.z * x2q;
        *(float2*)(out + (size_t)(rowA + 1) * 512 + 2 * t) =
            make_float2(csT.x * o1P + csT.y * o1Q, csT.z * o2P + csT.w * o2Q);
    }
#undef DQUAD
}

extern "C" void kernel_launch(void* const* d_in, const int* in_sizes, int n_in,
                              void* d_out, int out_size, void* d_ws, size_t ws_size,
                              hipStream_t stream) {
    const float* X          = (const float*)d_in[0];
    const float* scales     = (const float*)d_in[1];
    const float* angles     = (const float*)d_in[2];
    const float* act_bias   = (const float*)d_in[3];
    // d_in[4] act_activation — unused by the reference
    const float* act_curv   = (const float*)d_in[5];
    const float* bf_angles  = (const float*)d_in[6];
    // d_in[7] shuffle_perm — structural perfect shuffle, hardcoded
    const int*   recall_idx  = (const int*)d_in[8];
    const int*   out_mem_idx = (const int*)d_in[9];
    // d_in[10] bf_perm — structural perfect shuffle, hardcoded

    float* ws = (float*)d_ws;   // 462848 bytes used

    setup_kernel<<<201, 256, 0, stream>>>(angles, bf_angles, act_bias, act_curv,
                                          recall_idx, out_mem_idx, ws);
    sponge_kernel<<<NB / 2, 256, 0, stream>>>(X, scales, ws, (float*)d_out);
}